// Round 3
// baseline (139.920 us; speedup 1.0000x reference)
//
#include <hip/hip_runtime.h>
#include <cmath>

// CriticSNN forward: BATCH=65536, STATE_DIM=6, HIDDEN=128, NUM_STEPS=8, OUT=1
// One wave per batch-element pair; lane l owns neurons l and l+64.
// Spikes -> wave ballots; matmuls -> masked column sums from LDS.
// R3: plain (unswizzled) LDS layout -> 1 v_add per bit; packed fp32
// (v_pk_add/fma via ext-vector float2) -> halved VALU count; fused 4-mask
// walk retained for 4 ds_reads in flight.

typedef float v2f __attribute__((ext_vector_type(2)));
typedef float v4f __attribute__((ext_vector_type(4)));

constexpr int BATCH = 65536;
constexpr int HID   = 128;
constexpr int SDIM  = 6;
constexpr int NSTEP = 8;
constexpr int BLOCK = 1024;                         // 16 waves/block
constexpr int GRID  = 256;                          // 1 block per CU
constexpr int WAVES_TOTAL = GRID * (BLOCK / 64);    // 4096
constexpr int EPW   = BATCH / WAVES_TOTAL;          // 16 elems/wave (8 pairs)

__global__ __launch_bounds__(BLOCK) void snn_fwd(
    const float* __restrict__ state,
    const float* __restrict__ w_fc1,
    const float* __restrict__ w_rec1,
    const float* __restrict__ w_fc2,
    const float* __restrict__ w_rec2,
    const float* __restrict__ w_mean,
    const float* __restrict__ w_std,
    const float* __restrict__ p_alpha1, const float* __restrict__ p_beta1,
    const float* __restrict__ p_thr1,
    const float* __restrict__ p_alpha2, const float* __restrict__ p_beta2,
    const float* __restrict__ p_thr2,
    float* __restrict__ out)
{
    // entry(j,l) = {rec1[l][j], rec1[l+64][j], fc2[l][j], fc2[l+64][j]}
    // at plain index j*64+l. Wave read at (j<<6)|lane = contiguous 1KB block
    // -> conflict-free ds_read_b128, one v_add of scalar j*1024 per bit.
    __shared__ v4f  ld_w [HID * 64];    // 128 KiB
    __shared__ v2f  ld_fc1[SDIM * 64];  // 3 KiB
    __shared__ float ld_wm[HID];
    __shared__ float ld_wsd[HID];

    const int tid = threadIdx.x;

    // Staging: lane-fast (l = v&63) -> contiguous, conflict-free LDS writes.
    // Global reads are strided (uncoalesced) but one-time and L2-served.
    for (int v = tid; v < HID * 64; v += BLOCK) {
        const int l = v & 63, j = v >> 6;
        ld_w[v] = (v4f){ w_rec1[l * HID + j], w_rec1[(l + 64) * HID + j],
                         w_fc2 [l * HID + j], w_fc2 [(l + 64) * HID + j] };
    }
    for (int v = tid; v < SDIM * 64; v += BLOCK) {
        const int l = v & 63, k = v >> 6;
        ld_fc1[v] = (v2f){ w_fc1[l * SDIM + k], w_fc1[(l + 64) * SDIM + k] };
    }
    if (tid < HID)          ld_wm [tid]       = w_mean[tid];
    else if (tid < 2 * HID) ld_wsd[tid - HID] = w_std [tid - HID];

    const float a1 = fminf(fmaxf(p_alpha1[0], 0.f), 1.f);
    const float b1 = fminf(fmaxf(p_beta1 [0], 0.f), 1.f);
    const float a2 = fminf(fmaxf(p_alpha2[0], 0.f), 1.f);
    const float b2 = fminf(fmaxf(p_beta2 [0], 0.f), 1.f);
    const float t1 = p_thr1[0];
    const float t2 = p_thr2[0];
    const v2f a1v = {a1, a1}, b1v = {b1, b1}, a2v = {a2, a2}, b2v = {b2, b2};
    const v2f nt1 = {-t1, -t1}, nt2 = {-t2, -t2};

    __syncthreads();

    const int lane = tid & 63;
    const int gw   = blockIdx.x * (BLOCK / 64) + (tid >> 6);

    for (int e = 0; e < EPW / 2; ++e) {
        int bidx[2];
        bidx[0] = gw + WAVES_TOTAL * (2 * e);
        bidx[1] = gw + WAVES_TOTAL * (2 * e + 1);

        v2f cur[2];
        #pragma unroll
        for (int p = 0; p < 2; ++p) {
            v2f c = {0.f, 0.f};
            #pragma unroll
            for (int k = 0; k < SDIM; ++k) {
                const float s = state[bidx[p] * SDIM + k];   // wave-broadcast
                const v2f sv = {s, s};
                c = __builtin_elementwise_fma(sv, ld_fc1[(k << 6) | lane], c);
            }
            cur[p] = c;
        }

        v2f syn1[2] = {{0.f,0.f},{0.f,0.f}}, mem1[2] = {{0.f,0.f},{0.f,0.f}};
        v2f syn2[2] = {{0.f,0.f},{0.f,0.f}}, mem2[2] = {{0.f,0.f},{0.f,0.f}};
        v2f spk1f[2] = {{0.f,0.f},{0.f,0.f}}, spk2f[2] = {{0.f,0.f},{0.f,0.f}};
        v2f cnt[2] = {{0.f,0.f},{0.f,0.f}};
        v2f rr[2]  = {{0.f,0.f},{0.f,0.f}};   // rec1 contrib for NEXT step
        unsigned long long M2a[2] = {0ull, 0ull}, M2b[2] = {0ull, 0ull};

        #pragma unroll 1
        for (int t = 0; t < NSTEP; ++t) {
            // ----- layer 1 state update (rr from previous step's walk) -----
            bool pa0, pb0, pa1, pb1;
            #pragma unroll
            for (int p = 0; p < 2; ++p) {
                syn1[p] = __builtin_elementwise_fma(a1v, syn1[p], cur[p] + rr[p]);
                mem1[p] = __builtin_elementwise_fma(b1v, mem1[p], syn1[p]);
                mem1[p] = __builtin_elementwise_fma(spk1f[p], nt1, mem1[p]);
                rr[p] = (v2f){0.f, 0.f};
            }
            pa0 = (mem1[0].x - t1) > 0.f;  pb0 = (mem1[0].y - t1) > 0.f;
            pa1 = (mem1[1].x - t1) > 0.f;  pb1 = (mem1[1].y - t1) > 0.f;
            spk1f[0] = (v2f){ pa0 ? 1.f : 0.f, pb0 ? 1.f : 0.f };
            spk1f[1] = (v2f){ pa1 ? 1.f : 0.f, pb1 ? 1.f : 0.f };
            unsigned long long u0 = __ballot(pa0), v0 = __ballot(pb0);
            unsigned long long u1 = __ballot(pa1), v1 = __ballot(pb1);

            // ----- fused walk: fc2 (this step) + rec1 (next step) -----
            v2f ff[2] = {{0.f,0.f},{0.f,0.f}};
            while (u0 | v0 | u1 | v1) {
                if (u0) {
                    const int j = __builtin_ctzll(u0); u0 &= u0 - 1;
                    const v4f w = ld_w[(j << 6) | lane];
                    rr[0] += w.lo; ff[0] += w.hi;
                }
                if (v0) {
                    const int j = __builtin_ctzll(v0); v0 &= v0 - 1;
                    const v4f w = ld_w[((j + 64) << 6) | lane];
                    rr[0] += w.lo; ff[0] += w.hi;
                }
                if (u1) {
                    const int j = __builtin_ctzll(u1); u1 &= u1 - 1;
                    const v4f w = ld_w[(j << 6) | lane];
                    rr[1] += w.lo; ff[1] += w.hi;
                }
                if (v1) {
                    const int j = __builtin_ctzll(v1); v1 &= v1 - 1;
                    const v4f w = ld_w[((j + 64) << 6) | lane];
                    rr[1] += w.lo; ff[1] += w.hi;
                }
            }

            // ----- rec2 from PREVIOUS spk2 (almost never fires): global -----
            #pragma unroll
            for (int p = 0; p < 2; ++p) {
                unsigned long long m = M2a[p];
                while (m) {
                    const int j = __builtin_ctzll(m); m &= m - 1;
                    ff[p].x += w_rec2[lane * HID + j];
                    ff[p].y += w_rec2[(lane + 64) * HID + j];
                }
                m = M2b[p];
                while (m) {
                    const int j = __builtin_ctzll(m) + 64; m &= m - 1;
                    ff[p].x += w_rec2[lane * HID + j];
                    ff[p].y += w_rec2[(lane + 64) * HID + j];
                }
            }

            // ----- layer 2 state update -----
            bool qa0, qb0, qa1, qb1;
            #pragma unroll
            for (int p = 0; p < 2; ++p) {
                syn2[p] = __builtin_elementwise_fma(a2v, syn2[p], ff[p]);
                mem2[p] = __builtin_elementwise_fma(b2v, mem2[p], syn2[p]);
                mem2[p] = __builtin_elementwise_fma(spk2f[p], nt2, mem2[p]);
            }
            qa0 = (mem2[0].x - t2) > 0.f;  qb0 = (mem2[0].y - t2) > 0.f;
            qa1 = (mem2[1].x - t2) > 0.f;  qb1 = (mem2[1].y - t2) > 0.f;
            spk2f[0] = (v2f){ qa0 ? 1.f : 0.f, qb0 ? 1.f : 0.f };
            spk2f[1] = (v2f){ qa1 ? 1.f : 0.f, qb1 ? 1.f : 0.f };
            cnt[0] += spk2f[0];
            cnt[1] += spk2f[1];
            M2a[0] = __ballot(qa0); M2b[0] = __ballot(qb0);
            M2a[1] = __ballot(qa1); M2b[1] = __ballot(qb1);
        }

        // ----- heads -----
        float dm[2], ds[2];
        #pragma unroll
        for (int p = 0; p < 2; ++p) {
            const v2f avg = cnt[p] * 0.125f;
            dm[p] = avg.x * ld_wm [lane] + avg.y * ld_wm [lane + 64];
            ds[p] = avg.x * ld_wsd[lane] + avg.y * ld_wsd[lane + 64];
        }
        #pragma unroll
        for (int off = 32; off > 0; off >>= 1) {
            dm[0] += __shfl_xor(dm[0], off, 64);
            ds[0] += __shfl_xor(ds[0], off, 64);
            dm[1] += __shfl_xor(dm[1], off, 64);
            ds[1] += __shfl_xor(ds[1], off, 64);
        }
        if (lane == 0) {
            #pragma unroll
            for (int p = 0; p < 2; ++p) {
                out[bidx[p]] = tanhf(dm[p]);
                const float sg = 1.f / (1.f + expf(-(ds[p] + 2.f)));
                out[BATCH + bidx[p]] = 1.9f * sg + 0.1f;
            }
        }
    }
}

extern "C" void kernel_launch(void* const* d_in, const int* in_sizes, int n_in,
                              void* d_out, int out_size, void* d_ws, size_t ws_size,
                              hipStream_t stream) {
    (void)in_sizes; (void)n_in; (void)d_ws; (void)ws_size; (void)out_size;
    snn_fwd<<<GRID, BLOCK, 0, stream>>>(
        (const float*)d_in[0],  // state
        (const float*)d_in[1],  // w_fc1
        (const float*)d_in[2],  // w_rec1
        (const float*)d_in[3],  // w_fc2
        (const float*)d_in[4],  // w_rec2
        (const float*)d_in[5],  // w_mean
        (const float*)d_in[6],  // w_std
        (const float*)d_in[7],  // alpha1
        (const float*)d_in[8],  // beta1
        (const float*)d_in[9],  // thr1
        (const float*)d_in[10], // alpha2
        (const float*)d_in[11], // beta2
        (const float*)d_in[12], // thr2
        (float*)d_out);
}